// Round 3
// baseline (710.720 us; speedup 1.0000x reference)
//
#include <hip/hip_runtime.h>
#include <hip/hip_bf16.h>
#include <stdint.h>

#define N_NODES 100000
#define N_EDGES 1600000
#define HID 128
#define OUT_DIM 64
#define N_LAYERS 3

typedef __attribute__((ext_vector_type(8))) short short8;
typedef __attribute__((ext_vector_type(4))) float v4f;
typedef __attribute__((ext_vector_type(4))) unsigned short ushort4v;

__device__ __forceinline__ float bf2f(unsigned int lo16) {
    union { unsigned int i; float f; } v; v.i = lo16 << 16; return v.f;
}
__device__ __forceinline__ unsigned short f2bf(float f) {
    union { float f; unsigned int i; } v; v.f = f;
    unsigned int r = v.i + 0x7fffu + ((v.i >> 16) & 1u);  // RNE
    return (unsigned short)(r >> 16);
}

// ---------------- edge dtype detect (int64 vs int32 robustness) -----------
__global__ void detect_kernel(const int* __restrict__ raw, int* __restrict__ flag) {
    int is64 = 1;
    for (int i = 1; i < 128; i += 2)
        if (raw[i] != 0) { is64 = 0; break; }
    *flag = is64;
}

// ---------------- histogram of dst, straight off the raw edge buffer ------
// 4 edges per thread for ILP; atomics are fire-and-forget (no return use).
__global__ __launch_bounds__(256) void hist2(const int* __restrict__ raw,
                                             const int* __restrict__ flag,
                                             int* __restrict__ deg) {
    int t = blockIdx.x * blockDim.x + threadIdx.x;
    int e0 = t * 4;
    if (e0 >= N_EDGES) return;
    int d[4];
    if (*flag) {
        const long long* r = (const long long*)raw;
#pragma unroll
        for (int i = 0; i < 4; ++i) d[i] = (int)r[N_EDGES + e0 + i];
    } else {
#pragma unroll
        for (int i = 0; i < 4; ++i) d[i] = raw[N_EDGES + e0 + i];
    }
#pragma unroll
    for (int i = 0; i < 4; ++i) atomicAdd(&deg[d[i]], 1);
}

__global__ void scan1_kernel(const int* __restrict__ deg, int* __restrict__ incl,
                             int* __restrict__ bsums, int n) {
    __shared__ int tmp[1024];
    int tid = threadIdx.x;
    int i = blockIdx.x * 1024 + tid;
    int v = (i < n) ? deg[i] : 0;
    tmp[tid] = v;
    __syncthreads();
    for (int off = 1; off < 1024; off <<= 1) {
        int t = (tid >= off) ? tmp[tid - off] : 0;
        __syncthreads();
        tmp[tid] += t;
        __syncthreads();
    }
    if (i < n) incl[i] = tmp[tid];
    if (tid == 1023) bsums[blockIdx.x] = tmp[1023];
}

__global__ void scan2_kernel(int* __restrict__ bsums, int nb) {
    __shared__ int tmp[128];
    int tid = threadIdx.x;
    int v = (tid < nb) ? bsums[tid] : 0;
    tmp[tid] = v;
    __syncthreads();
    for (int off = 1; off < 128; off <<= 1) {
        int t = (tid >= off) ? tmp[tid - off] : 0;
        __syncthreads();
        tmp[tid] += t;
        __syncthreads();
    }
    if (tid < nb) bsums[tid] = tmp[tid] - v;  // exclusive
}

// row_off + inv_deg + cursor (cursor starts at row_off so fill needs no
// second random read)
__global__ void scan3_kernel(const int* __restrict__ incl, const int* __restrict__ deg,
                             const int* __restrict__ bsums, int* __restrict__ row_off,
                             int* __restrict__ cursor, float* __restrict__ inv_deg, int n) {
    int i = blockIdx.x * blockDim.x + threadIdx.x;
    if (i < n) {
        int ro = incl[i] - deg[i] + bsums[i >> 10];
        row_off[i] = ro;
        cursor[i] = ro;
        int d = deg[i];
        inv_deg[i] = 1.0f / (float)(d > 0 ? d : 1);
    } else if (i == n) {
        row_off[n] = N_EDGES;
    }
}

// ---------------- bucket fill: srcs_sorted[atomic(cursor[dst])] = src -----
// Reads raw edges directly; 4 independent latency chains per thread.
__global__ __launch_bounds__(256) void fill2(const int* __restrict__ raw,
                                             const int* __restrict__ flag,
                                             int* __restrict__ cursor,
                                             int* __restrict__ srcs_sorted) {
    int t = blockIdx.x * blockDim.x + threadIdx.x;
    int e0 = t * 4;
    if (e0 >= N_EDGES) return;
    int s[4], d[4];
    if (*flag) {
        const long long* r = (const long long*)raw;
#pragma unroll
        for (int i = 0; i < 4; ++i) {
            s[i] = (int)r[e0 + i];
            d[i] = (int)r[N_EDGES + e0 + i];
        }
    } else {
#pragma unroll
        for (int i = 0; i < 4; ++i) {
            s[i] = raw[e0 + i];
            d[i] = raw[N_EDGES + e0 + i];
        }
    }
    int p[4];
#pragma unroll
    for (int i = 0; i < 4; ++i) p[i] = atomicAdd(&cursor[d[i]], 1);
#pragma unroll
    for (int i = 0; i < 4; ++i) srcs_sorted[p[i]] = s[i];
}

// ---------------- weight prep: fp32 -> bf16 transposed -------------------
__global__ void prep_weights(const float* __restrict__ Wl, const float* __restrict__ Wr,
                             const float* __restrict__ fc_w,
                             unsigned short* __restrict__ WlT, unsigned short* __restrict__ WrT,
                             unsigned short* __restrict__ fcT) {
    int idx = blockIdx.x * blockDim.x + threadIdx.x;
    const int WELEMS = N_LAYERS * HID * HID;
    if (idx < WELEMS) {
        int l = idx / (HID * HID);
        int rem = idx - l * HID * HID;
        int k = rem / HID, nn2 = rem - k * HID;
        WlT[l * HID * HID + nn2 * HID + k] = f2bf(Wl[idx]);
        WrT[l * HID * HID + nn2 * HID + k] = f2bf(Wr[idx]);
    } else {
        int j = idx - WELEMS;
        if (j < N_LAYERS * HID * OUT_DIM) {
            int l = j / (HID * OUT_DIM);
            int rem = j - l * HID * OUT_DIM;
            int k = rem / OUT_DIM, o = rem - k * OUT_DIM;
            fcT[l * OUT_DIM * HID + o * HID + k] = f2bf(fc_w[(l * HID + k) * OUT_DIM + o]);
        }
    }
}

__global__ void convert_x(const float* __restrict__ x, unsigned short* __restrict__ xb) {
    int i = blockIdx.x * blockDim.x + threadIdx.x;
    if (i < N_NODES * HID / 4) {
        float4 v = ((const float4*)x)[i];
        ushort4v o;
        o[0] = f2bf(v.x); o[1] = f2bf(v.y); o[2] = f2bf(v.z); o[3] = f2bf(v.w);
        ((ushort4v*)xb)[i] = o;
    }
}

// ---------------- mean aggregation: one wave per node (bf16 h) -----------
__global__ __launch_bounds__(256) void agg_bf(
    const unsigned short* __restrict__ h, const int* __restrict__ srcs,
    const int* __restrict__ row_off, const float* __restrict__ inv_deg,
    unsigned short* __restrict__ meanb) {
    int node = blockIdx.x * 4 + (threadIdx.x >> 6);
    int lane = threadIdx.x & 63;
    if (node >= N_NODES) return;
    int beg = row_off[node], end = row_off[node + 1];
    const uint32_t* h2 = (const uint32_t*)h;
    float ax = 0.f, ay = 0.f;
    int t = beg;
    for (; t + 4 <= end; t += 4) {
        int s0 = srcs[t], s1 = srcs[t + 1], s2 = srcs[t + 2], s3 = srcs[t + 3];
        uint32_t v0 = h2[(size_t)s0 * 64 + lane];
        uint32_t v1 = h2[(size_t)s1 * 64 + lane];
        uint32_t v2 = h2[(size_t)s2 * 64 + lane];
        uint32_t v3 = h2[(size_t)s3 * 64 + lane];
        ax += bf2f(v0 & 0xffffu) + bf2f(v1 & 0xffffu) + bf2f(v2 & 0xffffu) + bf2f(v3 & 0xffffu);
        ay += bf2f(v0 >> 16) + bf2f(v1 >> 16) + bf2f(v2 >> 16) + bf2f(v3 >> 16);
    }
    for (; t < end; ++t) {
        uint32_t v0 = h2[(size_t)srcs[t] * 64 + lane];
        ax += bf2f(v0 & 0xffffu);
        ay += bf2f(v0 >> 16);
    }
    float id = inv_deg[node];
    ax *= id; ay *= id;
    uint32_t packed = (uint32_t)f2bf(ax) | ((uint32_t)f2bf(ay) << 16);
    ((uint32_t*)meanb)[(size_t)node * 64 + lane] = packed;
}

// ---------------- layer: H = relu(mean@Wl + h@Wr + b), bf16 MFMA ---------
__global__ __launch_bounds__(256) void layer_mfma(
    const unsigned short* __restrict__ Am,
    const unsigned short* __restrict__ Ah,
    const unsigned short* __restrict__ WlT,
    const unsigned short* __restrict__ WrT,
    const float* __restrict__ bias,
    unsigned short* __restrict__ Hout, int n) {
    int tid = threadIdx.x;
    int w = tid >> 6, L = tid & 63;
    int q = L >> 4, r16 = L & 15;
    int colbase = (w & 1) * 64;
    int nodebase = (w >> 1) * 64;
    int node0 = blockIdx.x * 128;

    v4f acc[4][4];
#pragma unroll
    for (int i = 0; i < 4; ++i)
#pragma unroll
        for (int j = 0; j < 4; ++j)
#pragma unroll
            for (int r = 0; r < 4; ++r) acc[i][j][r] = 0.f;

    int nd[4];
#pragma unroll
    for (int j = 0; j < 4; ++j) {
        int t = node0 + nodebase + j * 16 + r16;
        nd[j] = t < n ? t : n - 1;
    }

#pragma unroll
    for (int seg = 0; seg < 2; ++seg) {
        const unsigned short* A = seg ? Ah : Am;
        const unsigned short* WT = seg ? WrT : WlT;
#pragma unroll
        for (int t = 0; t < 4; ++t) {
            int koff = t * 32 + q * 8;
            short8 afr[4], bfr[4];
#pragma unroll
            for (int i = 0; i < 4; ++i)
                afr[i] = *(const short8*)&WT[(colbase + i * 16 + r16) * HID + koff];
#pragma unroll
            for (int j = 0; j < 4; ++j)
                bfr[j] = *(const short8*)&A[(size_t)nd[j] * HID + koff];
#pragma unroll
            for (int i = 0; i < 4; ++i)
#pragma unroll
                for (int j = 0; j < 4; ++j)
                    acc[i][j] = __builtin_amdgcn_mfma_f32_16x16x32_bf16(afr[i], bfr[j], acc[i][j], 0, 0, 0);
        }
    }

#pragma unroll
    for (int i = 0; i < 4; ++i) {
        int col = colbase + i * 16 + q * 4;
        float4 bv = *(const float4*)&bias[col];
#pragma unroll
        for (int j = 0; j < 4; ++j) {
            int node = node0 + nodebase + j * 16 + r16;
            if (node < n) {
                float v0 = acc[i][j][0] + bv.x;
                float v1 = acc[i][j][1] + bv.y;
                float v2 = acc[i][j][2] + bv.z;
                float v3 = acc[i][j][3] + bv.w;
                ushort4v o;
                o[0] = f2bf(v0 > 0.f ? v0 : 0.f);
                o[1] = f2bf(v1 > 0.f ? v1 : 0.f);
                o[2] = f2bf(v2 > 0.f ? v2 : 0.f);
                o[3] = f2bf(v3 > 0.f ? v3 : 0.f);
                *(ushort4v*)&Hout[(size_t)node * HID + col] = o;
            }
        }
    }
}

// ---------------- fused final FC: out = [h1 h2 h3] @ fc_w + fc_b ---------
// One kernel, K=384 over the three kept h buffers; out written exactly once.
__global__ __launch_bounds__(256) void fc_fused(
    const unsigned short* __restrict__ h0, const unsigned short* __restrict__ h1,
    const unsigned short* __restrict__ h2, const unsigned short* __restrict__ fcT,
    const float* __restrict__ fc_b, float* __restrict__ out, int n) {
    int tid = threadIdx.x;
    int w = tid >> 6, L = tid & 63;
    int q = L >> 4, r16 = L & 15;
    int node0 = blockIdx.x * 128 + w * 32;

    int nd[2], valid[2];
#pragma unroll
    for (int j = 0; j < 2; ++j) {
        int t = node0 + j * 16 + r16;
        valid[j] = t < n;
        nd[j] = valid[j] ? t : n - 1;
    }

    v4f acc[4][2];
#pragma unroll
    for (int i = 0; i < 4; ++i) {
        int col = i * 16 + q * 4;
        float4 bv = *(const float4*)&fc_b[col];
#pragma unroll
        for (int j = 0; j < 2; ++j) {
            acc[i][j][0] = bv.x; acc[i][j][1] = bv.y;
            acc[i][j][2] = bv.z; acc[i][j][3] = bv.w;
        }
    }

    const unsigned short* hs[3] = {h0, h1, h2};
#pragma unroll
    for (int l = 0; l < 3; ++l) {
        const unsigned short* H = hs[l];
        const unsigned short* F = fcT + (size_t)l * OUT_DIM * HID;
#pragma unroll
        for (int t = 0; t < 4; ++t) {
            int koff = t * 32 + q * 8;
            short8 afr[4], bfr[2];
#pragma unroll
            for (int i = 0; i < 4; ++i)
                afr[i] = *(const short8*)&F[(i * 16 + r16) * HID + koff];
#pragma unroll
            for (int j = 0; j < 2; ++j)
                bfr[j] = *(const short8*)&H[(size_t)nd[j] * HID + koff];
#pragma unroll
            for (int i = 0; i < 4; ++i)
#pragma unroll
                for (int j = 0; j < 2; ++j)
                    acc[i][j] = __builtin_amdgcn_mfma_f32_16x16x32_bf16(afr[i], bfr[j], acc[i][j], 0, 0, 0);
        }
    }

#pragma unroll
    for (int i = 0; i < 4; ++i) {
        int col = i * 16 + q * 4;
#pragma unroll
        for (int j = 0; j < 2; ++j) {
            if (valid[j])
                *(v4f*)&out[(size_t)nd[j] * OUT_DIM + col] = acc[i][j];
        }
    }
}

extern "C" void kernel_launch(void* const* d_in, const int* in_sizes, int n_in,
                              void* d_out, int out_size, void* d_ws, size_t ws_size,
                              hipStream_t stream) {
    const float* x     = (const float*)d_in[0];
    const int*   edges = (const int*)d_in[1];
    const float* Wl    = (const float*)d_in[2];
    const float* Wr    = (const float*)d_in[3];
    const float* b     = (const float*)d_in[4];
    const float* fc_w  = (const float*)d_in[5];
    const float* fc_b  = (const float*)d_in[6];
    float* out = (float*)d_out;

    char* ws = (char*)d_ws;
    size_t off = 0;
    auto alloc = [&](size_t bytes) {
        void* p = ws + off;
        off = (off + bytes + 255) & ~(size_t)255;
        return p;
    };
    int*   flag        = (int*)alloc(256);
    int*   deg         = (int*)alloc((size_t)N_NODES * 4);
    int*   incl        = (int*)alloc((size_t)N_NODES * 4);
    int*   bsums       = (int*)alloc(128 * 4);
    int*   row_off     = (int*)alloc((size_t)(N_NODES + 1) * 4);
    int*   cursor      = (int*)alloc((size_t)N_NODES * 4);
    float* inv_deg     = (float*)alloc((size_t)N_NODES * 4);
    int*   srcs_sorted = (int*)alloc((size_t)N_EDGES * 4);
    unsigned short* xb    = (unsigned short*)alloc((size_t)N_NODES * HID * 2);
    unsigned short* meanb = (unsigned short*)alloc((size_t)N_NODES * HID * 2);
    unsigned short* hA    = (unsigned short*)alloc((size_t)N_NODES * HID * 2);
    unsigned short* hB    = (unsigned short*)alloc((size_t)N_NODES * HID * 2);
    unsigned short* hC    = (unsigned short*)alloc((size_t)N_NODES * HID * 2);
    unsigned short* WlT   = (unsigned short*)alloc((size_t)N_LAYERS * HID * HID * 2);
    unsigned short* WrT   = (unsigned short*)alloc((size_t)N_LAYERS * HID * HID * 2);
    unsigned short* fcT   = (unsigned short*)alloc((size_t)N_LAYERS * OUT_DIM * HID * 2);

    hipMemsetAsync(deg, 0, (size_t)N_NODES * 4, stream);

    detect_kernel<<<1, 1, 0, stream>>>(edges, flag);
    hist2<<<(N_EDGES / 4 + 255) / 256, 256, 0, stream>>>(edges, flag, deg);
    int nb = (N_NODES + 1023) / 1024;
    scan1_kernel<<<nb, 1024, 0, stream>>>(deg, incl, bsums, N_NODES);
    scan2_kernel<<<1, 128, 0, stream>>>(bsums, nb);
    scan3_kernel<<<(N_NODES + 1 + 255) / 256, 256, 0, stream>>>(incl, deg, bsums, row_off, cursor, inv_deg, N_NODES);
    fill2<<<(N_EDGES / 4 + 255) / 256, 256, 0, stream>>>(edges, flag, cursor, srcs_sorted);

    prep_weights<<<(N_LAYERS * HID * HID + N_LAYERS * HID * OUT_DIM + 255) / 256, 256, 0, stream>>>(
        Wl, Wr, fc_w, WlT, WrT, fcT);
    convert_x<<<(N_NODES * HID / 4 + 255) / 256, 256, 0, stream>>>(x, xb);

    unsigned short* hbufs[3] = {hA, hB, hC};
    const unsigned short* hprev = xb;
    int ngrid = (N_NODES + 127) / 128;
    for (int l = 0; l < N_LAYERS; ++l) {
        unsigned short* hcur = hbufs[l];
        agg_bf<<<(N_NODES + 3) / 4, 256, 0, stream>>>(hprev, srcs_sorted, row_off, inv_deg, meanb);
        layer_mfma<<<ngrid, 256, 0, stream>>>(
            meanb, hprev, WlT + (size_t)l * HID * HID, WrT + (size_t)l * HID * HID,
            b + (size_t)l * HID, hcur, N_NODES);
        hprev = hcur;
    }
    fc_fused<<<ngrid, 256, 0, stream>>>(hA, hB, hC, fcT, fc_b, out, N_NODES);
}